// Round 7
// baseline (183.857 us; speedup 1.0000x reference)
//
#include <hip/hip_runtime.h>

// B=32, N=1024, D=256. out = softmax((x Wq^T + bq)(x Wk^T + bk)^T) (x Wv^T + bv)
// fp16 MFMA, fp32 accumulate.
// R12 (resubmit; infra failure last round): proj de-staged. pw (0.4 MB) is
// L2-resident on every XCD; LDS staging + 2 barriers/iter was pure overhead
// (guide common-mistake #7 / m169). proj reads W fragments straight from pw
// (lane-consecutive 1 KB coalesced L2 reads), ZERO barriers (epilogue is
// wave-private), bias hoisted to registers, e-loop fully unrolled.
// attn unchanged from R11 (63.1 us, conflicts 0).
#define NN 1024
#define DD 256

typedef __attribute__((ext_vector_type(8))) _Float16 f16x8;  // 8 fp16 = 4 VGPRs
typedef __attribute__((ext_vector_type(4))) _Float16 f16x4;  // 4 fp16 = 2 VGPRs
typedef __attribute__((ext_vector_type(4))) float f32x4;

union H8 { f16x8 v; _Float16 s[8]; };

__device__ __forceinline__ void g2lds16(const void* g, void* l) {
  __builtin_amdgcn_global_load_lds(
      (const __attribute__((address_space(1))) void*)g,
      (__attribute__((address_space(3))) void*)l, 16, 0, 0);
}

// ---------------- kernel 1: pack W fp32 -> fp16 fragment-major (32-col tiles) -------
// chunk c = ((et*8+kk)*2+nt)*64+lane ; data = W[e=et*32+nt*16+c16][d=kk*32+qd*8..+7]
__global__ void wconv_kernel(const float* __restrict__ Wq, const float* __restrict__ Wk,
                             const float* __restrict__ Wv, _Float16* __restrict__ pw) {
  int c = blockIdx.x * 256 + threadIdx.x;        // < 24576
  int lane = c & 63;
  int nt = (c >> 6) & 1;
  int kk = (c >> 7) & 7;
  int et = c >> 10;                              // 0..23
  int e = et * 32 + nt * 16 + (lane & 15);
  int d = kk * 32 + (lane >> 4) * 8;
  const float* W = (e < 256) ? Wq : (e < 512 ? Wk : Wv);
  const float* src = W + (e & 255) * 256 + d;
  H8 xx;
  for (int j = 0; j < 8; ++j) xx.s[j] = (_Float16)src[j];
  *(f16x8*)(pw + (size_t)c * 8) = xx.v;
}

// ---------------- kernel 2: QKV projection -------------------------------------------
// grid 512 = 256 m-tiles x 2 e-halves; 4 waves, wave owns 32 m-rows (2 A-sets).
// W fragments read DIRECTLY from L2-resident pw (no LDS staging, no barriers).
__global__ __launch_bounds__(256, 2) void proj_kernel(
    const float* __restrict__ traj,
    const float* __restrict__ bq, const float* __restrict__ bk, const float* __restrict__ bv,
    const _Float16* __restrict__ pw,
    _Float16* __restrict__ pq, _Float16* __restrict__ pk, _Float16* __restrict__ pv)
{
  __shared__ alignas(16) _Float16 Cs[4][1280];   // per-wave 32x40 staging (2.5 KB each)

  const int t = threadIdx.x;
  const int lane = t & 63, wave = t >> 6;
  const int col16 = lane & 15, quad = lane >> 4;
  const int mt = blockIdx.x >> 1, eh = blockIdx.x & 1;
  const int mbase = mt * 128;
  const int bb = mbase >> 10;

  // A fragments, 2 sets of 16 rows (rows mbase + wave*32 + s*16 + col16)
  f16x8 aq[2][8];
#pragma unroll
  for (int s = 0; s < 2; ++s) {
    const float* ap = traj + (size_t)(mbase + wave * 32 + s * 16 + col16) * DD;
#pragma unroll
    for (int kk = 0; kk < 8; ++kk) {
      float4 u0 = *(const float4*)(ap + kk * 32 + quad * 8);
      float4 u1 = *(const float4*)(ap + kk * 32 + quad * 8 + 4);
      H8 xx;
      xx.s[0] = (_Float16)u0.x; xx.s[1] = (_Float16)u0.y;
      xx.s[2] = (_Float16)u0.z; xx.s[3] = (_Float16)u0.w;
      xx.s[4] = (_Float16)u1.x; xx.s[5] = (_Float16)u1.y;
      xx.s[6] = (_Float16)u1.z; xx.s[7] = (_Float16)u1.w;
      aq[s][kk] = xx.v;
    }
  }

  // bias prologue: all 24 scalars into registers (static indices -> no scratch)
  float biasv[12][2];
#pragma unroll
  for (int ei = 0; ei < 12; ++ei) {
    int e0 = eh * 384 + ei * 32;
    int sel = e0 >> 8;                 // 0=q 1=k 2=v (wave-uniform)
    const float* bias = (sel == 0) ? bq : (sel == 1 ? bk : bv);
#pragma unroll
    for (int nt = 0; nt < 2; ++nt)
      biasv[ei][nt] = bias[(e0 & 255) + nt * 16 + col16];
  }

  const f32x4 zero = {0.f, 0.f, 0.f, 0.f};
  const _Float16* wbase = pw + (size_t)(eh * 12) * 8192 + (size_t)lane * 8;

#pragma unroll
  for (int ei = 0; ei < 12; ++ei) {
    const _Float16* wt = wbase + (size_t)ei * 8192;

    f32x4 acc[2][2];
    acc[0][0] = zero; acc[0][1] = zero; acc[1][0] = zero; acc[1][1] = zero;
#pragma unroll
    for (int kk = 0; kk < 8; ++kk)
#pragma unroll
      for (int nt = 0; nt < 2; ++nt) {
        f16x8 bw = *(const f16x8*)(wt + (size_t)((kk * 2 + nt) * 64) * 8);
        acc[0][nt] = __builtin_amdgcn_mfma_f32_16x16x32_f16(aq[0][kk], bw, acc[0][nt], 0, 0, 0);
        acc[1][nt] = __builtin_amdgcn_mfma_f32_16x16x32_f16(aq[1][kk], bw, acc[1][nt], 0, 0, 0);
      }

    int e0 = eh * 384 + ei * 32;
    int sel = e0 >> 8;                 // 0=q 1=k 2=v
#pragma unroll
    for (int nt = 0; nt < 2; ++nt) {
      float bvl = biasv[ei][nt];
#pragma unroll
      for (int s = 0; s < 2; ++s) {
        acc[s][nt][0] += bvl; acc[s][nt][1] += bvl;
        acc[s][nt][2] += bvl; acc[s][nt][3] += bvl;
      }
    }

    _Float16* cs = Cs[wave];           // wave-private: in-order DS pipe, no barriers
    if (sel < 2) {
      // C-layout staging: row = s*16+quad*4+r (stride 40), col = nt*16+col16
#pragma unroll
      for (int s = 0; s < 2; ++s)
#pragma unroll
        for (int nt = 0; nt < 2; ++nt)
#pragma unroll
          for (int r = 0; r < 4; ++r)
            cs[(s * 16 + quad * 4 + r) * 40 + nt * 16 + col16] = (_Float16)acc[s][nt][r];
      if (sel == 0) {
#pragma unroll
        for (int s = 0; s < 2; ++s) {
          f16x8 val = *(const f16x8*)&cs[(s * 16 + col16) * 40 + quad * 8];
          int g = (mbase >> 4) + wave * 2 + s;
          *(f16x8*)(pq + (size_t)((g * 8 + ei) * 64 + lane) * 8) = val;   // kk = ei (eh=0)
        }
      } else {
        int kkg = (e0 - 256) >> 5;
#pragma unroll
        for (int s = 0; s < 2; ++s) {
          f16x8 val = *(const f16x8*)&cs[(s * 16 + col16) * 40 + quad * 8];
          int kgg = ((mbase & 1023) >> 4) + wave * 2 + s;
          *(f16x8*)(pk + (size_t)(((bb * 64 + kgg) * 8 + kkg) * 64 + lane) * 8) = val;
        }
      }
    } else {
      // transposed staging: row = e_local = nt*16+col16 (stride 40), col = m 0..31
#pragma unroll
      for (int s = 0; s < 2; ++s)
#pragma unroll
        for (int nt = 0; nt < 2; ++nt)
#pragma unroll
          for (int r = 0; r < 4; ++r)
            cs[(nt * 16 + col16) * 40 + s * 16 + quad * 4 + r] = (_Float16)acc[s][nt][r];
      int kt32 = ((mbase & 1023) >> 5) + wave;   // wave's 32 rows = one 32-key group
#pragma unroll
      for (int dtl = 0; dtl < 2; ++dtl) {
        // key permutation pi baked in: slot j holds local key (j>>2)*16 + quad*4 + (j&3)
        // -> matches attn's swapped-QK P layout, so PV needs no shuffle/spill.
        const _Float16* base = &cs[(dtl * 16 + col16) * 40];
        H8 val;
        *(f16x4*)&val.s[0] = *(const f16x4*)&base[quad * 4];
        *(f16x4*)&val.s[4] = *(const f16x4*)&base[16 + quad * 4];
        int dtg = ((e0 - 512) >> 4) + dtl;
        *(f16x8*)(pv + (size_t)(((bb * 32 + kt32) * 16 + dtg) * 64 + lane) * 8) = val.v;
      }
    }
  }
}

// ---------------- kernel 3: flash attention ------------------------------------------
// grid (32 b, 16 qt) x 256 thr; 4 waves x 16 q-rows. K,V both double-buffered
// (64 KB LDS, 2 blocks/CU). Depth-2 prefetch, counted vmcnt(8) + raw s_barrier:
// no vmcnt(0) drain in the loop. Swapped QK^T -> in-register softmax (lane owns
// q-row col16; keys nt*16+quad*4+r); pv packing is pre-permuted so the exp'd P
// registers feed PV's A-operand directly. T13 defer-max THR=8.
__global__ __launch_bounds__(256, 2) void attn_kernel(
    const _Float16* __restrict__ pq, const _Float16* __restrict__ pk,
    const _Float16* __restrict__ pv, float* __restrict__ out)
{
  __shared__ alignas(16) _Float16 Ks[2][8192];   // 2 x 16 KB (32 keys x 256 d)
  __shared__ alignas(16) _Float16 Vs[2][8192];   // 2 x 16 KB

  const int t = threadIdx.x;
  const int lane = t & 63, wave = t >> 6;
  const int col16 = lane & 15, quad = lane >> 4;
  const int b = blockIdx.x, qt = blockIdx.y;     // bid%8 = b%8 -> per-batch XCD
  const int qrow0 = b * NN + qt * 64;

  // Q fragments from packed global (issued before staging: retired by first vmcnt(8))
  f16x8 aq[8];
  {
    int g = b * 64 + qt * 4 + wave;
#pragma unroll
    for (int kk = 0; kk < 8; ++kk)
      aq[kk] = *(const f16x8*)(pq + (size_t)((g * 8 + kk) * 64 + lane) * 8);
  }

  float m_i = -3.0e38f, l_i = 0.f;    // lane's q-row = col16
  f32x4 O[16];
  const f32x4 zero = {0.f, 0.f, 0.f, 0.f};
#pragma unroll
  for (int dt = 0; dt < 16; ++dt) O[dt] = zero;

  const _Float16* kbb = pk + (size_t)b * 64 * 8 * 64 * 8;
  const _Float16* vbb = pv + (size_t)b * 32 * 16 * 64 * 8;

  // prologue: stage tiles 0 and 1 (groups of 8 loads per tile: K then V)
#pragma unroll
  for (int i = 0; i < 4; ++i) g2lds16(kbb + (size_t)(i * 256 + t) * 8, &Ks[0][(i * 256 + t) * 8]);
#pragma unroll
  for (int i = 0; i < 4; ++i) g2lds16(vbb + (size_t)(i * 256 + t) * 8, &Vs[0][(i * 256 + t) * 8]);
#pragma unroll
  for (int i = 0; i < 4; ++i) g2lds16(kbb + 8192 + (size_t)(i * 256 + t) * 8, &Ks[1][(i * 256 + t) * 8]);
#pragma unroll
  for (int i = 0; i < 4; ++i) g2lds16(vbb + 8192 + (size_t)(i * 256 + t) * 8, &Vs[1][(i * 256 + t) * 8]);

  for (int kt = 0; kt < 32; ++kt) {
    // counted wait: oldest 8 outstanding = this iter's K,V tile; tile kt+1 stays in flight
    if (kt < 31) asm volatile("s_waitcnt vmcnt(8)" ::: "memory");
    else         asm volatile("s_waitcnt vmcnt(0)" ::: "memory");
    __builtin_amdgcn_s_barrier();      // A: everyone's tile-kt loads retired;
    asm volatile("" ::: "memory");     //    everyone's prev-iter LDS reads consumed

    // S' = K Q^T (swapped operands; A/B fragment layouts identical for this shape)
    const _Float16* ks = Ks[kt & 1];
    f32x4 S[2]; S[0] = zero; S[1] = zero;
    __builtin_amdgcn_s_setprio(1);
#pragma unroll
    for (int kk = 0; kk < 8; ++kk)
#pragma unroll
      for (int nt = 0; nt < 2; ++nt) {
        f16x8 bk_ = *(const f16x8*)&ks[((nt * 8 + kk) * 64 + lane) * 8];
        S[nt] = __builtin_amdgcn_mfma_f32_16x16x32_f16(bk_, aq[kk], S[nt], 0, 0, 0);
      }
    __builtin_amdgcn_s_setprio(0);

    // in-register softmax: lane holds S[q=col16][key = nt*16+quad*4+r]
    float sv[8];
#pragma unroll
    for (int nt = 0; nt < 2; ++nt)
#pragma unroll
      for (int r = 0; r < 4; ++r) sv[nt * 4 + r] = S[nt][r];
    float vmax = sv[0];
#pragma unroll
    for (int j = 1; j < 8; ++j) vmax = fmaxf(vmax, sv[j]);
    vmax = fmaxf(vmax, __shfl_xor(vmax, 16));
    vmax = fmaxf(vmax, __shfl_xor(vmax, 32));

    // T13 defer-max: rescale only when some row's max jumped by > 8
    if (__ballot(vmax > m_i + 8.0f)) {
      float nm = fmaxf(m_i, vmax);
      float alpha = __expf(m_i - nm);
      float a4[4];
#pragma unroll
      for (int r = 0; r < 4; ++r) a4[r] = __shfl(alpha, quad * 4 + r);
#pragma unroll
      for (int dt = 0; dt < 16; ++dt)
#pragma unroll
        for (int r = 0; r < 4; ++r) O[dt][r] *= a4[r];
      l_i *= alpha;
      m_i = nm;
    }
    float rs = 0.f;
    H8 px;
#pragma unroll
    for (int j = 0; j < 8; ++j) {
      float pj = __expf(sv[j] - m_i);  // bounded by e^8 = 2981 < fp16 max
      rs += pj;
      px.s[j] = (_Float16)pj;
    }
    rs += __shfl_xor(rs, 16);
    rs += __shfl_xor(rs, 32);
    l_i += rs;
    f16x8 ap = px.v;                   // PV A-operand straight from registers (pi-matched pv)

    // O += P V
    const _Float16* vs = Vs[kt & 1];
    __builtin_amdgcn_s_setprio(1);
#pragma unroll
    for (int dt = 0; dt < 16; ++dt) {
      f16x8 bv_ = *(const f16x8*)&vs[(dt * 64 + lane) * 8];
      O[dt] = __builtin_amdgcn_mfma_f32_16x16x32_f16(ap, bv_, O[dt], 0, 0, 0);
    }
    __builtin_amdgcn_s_setprio(0);

    asm volatile("" ::: "memory");
    __builtin_amdgcn_s_barrier();      // B: all waves done reading buffers [kt&1]
    if (kt < 30) {                     // depth-2: tile kt+2 -> buffers [kt&1]
      const _Float16* kg = kbb + (size_t)(kt + 2) * 8192;
      const _Float16* vg = vbb + (size_t)(kt + 2) * 8192;
      _Float16* kd = Ks[kt & 1];
      _Float16* vd = Vs[kt & 1];
#pragma unroll
      for (int i = 0; i < 4; ++i) g2lds16(kg + (size_t)(i * 256 + t) * 8, kd + (i * 256 + t) * 8);
#pragma unroll
      for (int i = 0; i < 4; ++i) g2lds16(vg + (size_t)(i * 256 + t) * 8, vd + (i * 256 + t) * 8);
    }
  }

  // epilogue: O /= l (broadcast l to C-layout), fp32 store
  float linv[4];
#pragma unroll
  for (int r = 0; r < 4; ++r) linv[r] = 1.0f / __shfl(l_i, quad * 4 + r);
#pragma unroll
  for (int r = 0; r < 4; ++r) {
    float* orow = out + (size_t)(qrow0 + wave * 16 + quad * 4 + r) * DD;
#pragma unroll
    for (int dt = 0; dt < 16; ++dt)
      orow[dt * 16 + col16] = O[dt][r] * linv[r];
  }
}

// ---------------- launch -------------------------------------------------------------
extern "C" void kernel_launch(void* const* d_in, const int* in_sizes, int n_in,
                              void* d_out, int out_size, void* d_ws, size_t ws_size,
                              hipStream_t stream) {
  const float* traj = (const float*)d_in[0];
  const float* Wq   = (const float*)d_in[1];
  const float* bq   = (const float*)d_in[2];
  const float* Wk   = (const float*)d_in[3];
  const float* bk   = (const float*)d_in[4];
  const float* Wv   = (const float*)d_in[5];
  const float* bv   = (const float*)d_in[6];

  // workspace (fp16): pq 16MB | pk 16MB | pv 16MB | pw 0.4MB  (all packed fragment-major)
  _Float16* pq = (_Float16*)d_ws;
  _Float16* pk = pq + (size_t)32768 * 256;
  _Float16* pv = pk + (size_t)32768 * 256;
  _Float16* pw = pv + (size_t)32768 * 256;   // ~48.4 MB total

  wconv_kernel<<<96, 256, 0, stream>>>(Wq, Wk, Wv, pw);
  proj_kernel<<<512, 256, 0, stream>>>(traj, bq, bk, bv, pw, pq, pk, pv);
  attn_kernel<<<dim3(32, 16), 256, 0, stream>>>(pq, pk, pv, (float*)d_out);
}

// Round 8
// 163.801 us; speedup vs baseline: 1.1224x; 1.1224x over previous
//
#include <hip/hip_runtime.h>

// B=32, N=1024, D=256. out = softmax((x Wq^T + bq)(x Wk^T + bk)^T) (x Wv^T + bv)
// fp16 MFMA, fp32 accumulate.
// R13: proj reverted to R11 staged version (R12 de-staging hurt: 16 scattered L2
// loads on the MFMA critical path beat the prefetched LDS pipeline it replaced).
// attn: T15 software pipeline -- iter kt runs QK(kt), SM(kt-1), PV(kt-1); the
// three phases are mutually independent so softmax VALU hides under MFMA.
// K depth-2 / V depth-1 prefetch, vmcnt(8)/(4 at kt=31)/(0 tail), 64 KB LDS,
// 2 blocks/CU, 8 waves/CU unchanged.
#define NN 1024
#define DD 256

typedef __attribute__((ext_vector_type(8))) _Float16 f16x8;  // 8 fp16 = 4 VGPRs
typedef __attribute__((ext_vector_type(4))) _Float16 f16x4;  // 4 fp16 = 2 VGPRs
typedef __attribute__((ext_vector_type(4))) float f32x4;

union H8 { f16x8 v; _Float16 s[8]; };

__device__ __forceinline__ void g2lds16(const void* g, void* l) {
  __builtin_amdgcn_global_load_lds(
      (const __attribute__((address_space(1))) void*)g,
      (__attribute__((address_space(3))) void*)l, 16, 0, 0);
}

// ---------------- kernel 1: pack W fp32 -> fp16 fragment-major (32-col tiles) -------
// chunk c = ((et*8+kk)*2+nt)*64+lane ; data = W[e=et*32+nt*16+c16][d=kk*32+qd*8..+7]
__global__ void wconv_kernel(const float* __restrict__ Wq, const float* __restrict__ Wk,
                             const float* __restrict__ Wv, _Float16* __restrict__ pw) {
  int c = blockIdx.x * 256 + threadIdx.x;        // < 24576
  int lane = c & 63;
  int nt = (c >> 6) & 1;
  int kk = (c >> 7) & 7;
  int et = c >> 10;                              // 0..23
  int e = et * 32 + nt * 16 + (lane & 15);
  int d = kk * 32 + (lane >> 4) * 8;
  const float* W = (e < 256) ? Wq : (e < 512 ? Wk : Wv);
  const float* src = W + (e & 255) * 256 + d;
  H8 xx;
  for (int j = 0; j < 8; ++j) xx.s[j] = (_Float16)src[j];
  *(f16x8*)(pw + (size_t)c * 8) = xx.v;
}

// ---------------- kernel 2: QKV projection (R11 staged version, measured-good) ------
// grid 512 = 256 m-tiles x 2 e-halves; 4 waves, wave owns 32 m-rows (2 A-sets).
// 32-col W tiles dbuf'd via global_load_lds with counted vmcnt (no vmcnt(0) drain
// mid-loop); all epilogues wave-private (no barriers needed for Cs).
__global__ __launch_bounds__(256, 2) void proj_kernel(
    const float* __restrict__ traj,
    const float* __restrict__ bq, const float* __restrict__ bk, const float* __restrict__ bv,
    const _Float16* __restrict__ pw,
    _Float16* __restrict__ pq, _Float16* __restrict__ pk, _Float16* __restrict__ pv)
{
  __shared__ alignas(16) _Float16 Wl[2][8192];   // 2 x 16 KB W tiles
  __shared__ alignas(16) _Float16 Cs[4][1280];   // per-wave 32x40 staging (2.5 KB each)

  const int t = threadIdx.x;
  const int lane = t & 63, wave = t >> 6;
  const int col16 = lane & 15, quad = lane >> 4;
  const int mt = blockIdx.x >> 1, eh = blockIdx.x & 1;
  const int mbase = mt * 128;
  const int bb = mbase >> 10;

  // A fragments, 2 sets of 16 rows (rows mbase + wave*32 + s*16 + col16)
  f16x8 aq[2][8];
  for (int s = 0; s < 2; ++s) {
    const float* ap = traj + (size_t)(mbase + wave * 32 + s * 16 + col16) * DD;
    for (int kk = 0; kk < 8; ++kk) {
      float4 u0 = *(const float4*)(ap + kk * 32 + quad * 8);
      float4 u1 = *(const float4*)(ap + kk * 32 + quad * 8 + 4);
      H8 xx;
      xx.s[0] = (_Float16)u0.x; xx.s[1] = (_Float16)u0.y;
      xx.s[2] = (_Float16)u0.z; xx.s[3] = (_Float16)u0.w;
      xx.s[4] = (_Float16)u1.x; xx.s[5] = (_Float16)u1.y;
      xx.s[6] = (_Float16)u1.z; xx.s[7] = (_Float16)u1.w;
      aq[s][kk] = xx.v;
    }
  }

  const f32x4 zero = {0.f, 0.f, 0.f, 0.f};
  const int et0 = eh * 12;

  // prologue: stage W tiles 0 and 1 (4 g2lds16 per tile per thread)
  for (int i = 0; i < 4; ++i)
    g2lds16(pw + (size_t)et0 * 8192 + (size_t)(i * 256 + t) * 8, Wl[0] + (i * 256 + t) * 8);
  for (int i = 0; i < 4; ++i)
    g2lds16(pw + (size_t)(et0 + 1) * 8192 + (size_t)(i * 256 + t) * 8, Wl[1] + (i * 256 + t) * 8);

  for (int ei = 0; ei < 12; ++ei) {
    // counted wait: oldest outstanding = tile ei. Steady state: tile ei+1 (4) +
    // prev epilogue's 2 global stores stay in flight -> vmcnt(6).
    if (ei == 0)      asm volatile("s_waitcnt vmcnt(4)" ::: "memory");
    else if (ei < 11) asm volatile("s_waitcnt vmcnt(6)" ::: "memory");
    else              asm volatile("s_waitcnt vmcnt(0)" ::: "memory");
    __builtin_amdgcn_s_barrier();      // tile ei landed for all waves
    asm volatile("" ::: "memory");

    const _Float16* wl = Wl[ei & 1];

    f32x4 acc[2][2];
    acc[0][0] = zero; acc[0][1] = zero; acc[1][0] = zero; acc[1][1] = zero;
    for (int kk = 0; kk < 8; ++kk)
      for (int nt = 0; nt < 2; ++nt) {
        f16x8 bw = *(const f16x8*)&wl[((kk * 2 + nt) * 64 + lane) * 8];
        acc[0][nt] = __builtin_amdgcn_mfma_f32_16x16x32_f16(aq[0][kk], bw, acc[0][nt], 0, 0, 0);
        acc[1][nt] = __builtin_amdgcn_mfma_f32_16x16x32_f16(aq[1][kk], bw, acc[1][nt], 0, 0, 0);
      }

    int e0 = eh * 384 + ei * 32;
    int sel = e0 >> 8;                 // 0=q 1=k 2=v
    const float* bias = (sel == 0) ? bq : (sel == 1 ? bk : bv);
    for (int nt = 0; nt < 2; ++nt) {
      float bvl = bias[(e0 & 255) + nt * 16 + col16];
      for (int s = 0; s < 2; ++s) {
        acc[s][nt][0] += bvl; acc[s][nt][1] += bvl;
        acc[s][nt][2] += bvl; acc[s][nt][3] += bvl;
      }
    }

    _Float16* cs = Cs[wave];           // wave-private: in-order DS pipe, no barriers
    if (sel < 2) {
      // C-layout staging: row = s*16+quad*4+r (stride 40), col = nt*16+col16
      for (int s = 0; s < 2; ++s)
        for (int nt = 0; nt < 2; ++nt)
          for (int r = 0; r < 4; ++r)
            cs[(s * 16 + quad * 4 + r) * 40 + nt * 16 + col16] = (_Float16)acc[s][nt][r];
      if (sel == 0) {
        for (int s = 0; s < 2; ++s) {
          f16x8 val = *(const f16x8*)&cs[(s * 16 + col16) * 40 + quad * 8];
          int g = (mbase >> 4) + wave * 2 + s;
          *(f16x8*)(pq + (size_t)((g * 8 + ei) * 64 + lane) * 8) = val;   // kk = ei (eh=0)
        }
      } else {
        int kkg = (e0 - 256) >> 5;
        for (int s = 0; s < 2; ++s) {
          f16x8 val = *(const f16x8*)&cs[(s * 16 + col16) * 40 + quad * 8];
          int kgg = ((mbase & 1023) >> 4) + wave * 2 + s;
          *(f16x8*)(pk + (size_t)(((bb * 64 + kgg) * 8 + kkg) * 64 + lane) * 8) = val;
        }
      }
    } else {
      // transposed staging: row = e_local = nt*16+col16 (stride 40), col = m 0..31
      for (int s = 0; s < 2; ++s)
        for (int nt = 0; nt < 2; ++nt)
          for (int r = 0; r < 4; ++r)
            cs[(nt * 16 + col16) * 40 + s * 16 + quad * 4 + r] = (_Float16)acc[s][nt][r];
      int kt32 = ((mbase & 1023) >> 5) + wave;   // wave's 32 rows = one 32-key group
      for (int dtl = 0; dtl < 2; ++dtl) {
        // key permutation pi baked in: slot j holds local key (j>>2)*16 + quad*4 + (j&3)
        // -> matches attn's swapped-QK P layout, so PV needs no shuffle/spill.
        const _Float16* base = &cs[(dtl * 16 + col16) * 40];
        H8 val;
        *(f16x4*)&val.s[0] = *(const f16x4*)&base[quad * 4];
        *(f16x4*)&val.s[4] = *(const f16x4*)&base[16 + quad * 4];
        int dtg = ((e0 - 512) >> 4) + dtl;
        *(f16x8*)(pv + (size_t)(((bb * 32 + kt32) * 16 + dtg) * 64 + lane) * 8) = val.v;
      }
    }

    asm volatile("" ::: "memory");
    __builtin_amdgcn_s_barrier();      // all waves done reading Wl[ei&1]
    if (ei < 10) {                     // issue tile ei+2 into the retired buffer
      const _Float16* ws = pw + (size_t)(et0 + ei + 2) * 8192;
      _Float16* wd = Wl[ei & 1];
      for (int i = 0; i < 4; ++i)
        g2lds16(ws + (size_t)(i * 256 + t) * 8, wd + (i * 256 + t) * 8);
    }
  }
}

// ---------------- kernel 3: flash attention (T15 pipelined) --------------------------
// grid (32 b, 16 qt) x 256 thr; 4 waves x 16 q-rows. Iteration kt computes QK(kt),
// then SM(kt-1) (operands one iter old -> no stall), then PV(kt-1): softmax VALU
// hides under MFMA. K depth-2 / V depth-1 prefetch into 2+2 buffers (64 KB LDS,
// 2 blocks/CU). vmcnt(8) steady, vmcnt(4) at kt=31, vmcnt(0) tail only.
__global__ __launch_bounds__(256, 2) void attn_kernel(
    const _Float16* __restrict__ pq, const _Float16* __restrict__ pk,
    const _Float16* __restrict__ pv, float* __restrict__ out)
{
  __shared__ alignas(16) _Float16 Ks[2][8192];   // 2 x 16 KB (32 keys x 256 d)
  __shared__ alignas(16) _Float16 Vs[2][8192];   // 2 x 16 KB

  const int t = threadIdx.x;
  const int lane = t & 63, wave = t >> 6;
  const int col16 = lane & 15, quad = lane >> 4;
  const int b = blockIdx.x, qt = blockIdx.y;     // bid%8 = b%8 -> per-batch XCD
  const int qrow0 = b * NN + qt * 64;

  // Q fragments from packed global (issued before staging: retired by first vmcnt(8))
  f16x8 aq[8];
  {
    int g = b * 64 + qt * 4 + wave;
#pragma unroll
    for (int kk = 0; kk < 8; ++kk)
      aq[kk] = *(const f16x8*)(pq + (size_t)((g * 8 + kk) * 64 + lane) * 8);
  }

  float m_i = -3.0e38f, l_i = 0.f;    // lane's q-row = col16
  f32x4 O[16];
  const f32x4 zero = {0.f, 0.f, 0.f, 0.f};
#pragma unroll
  for (int dt = 0; dt < 16; ++dt) O[dt] = zero;

  const _Float16* kbb = pk + (size_t)b * 64 * 8 * 64 * 8;
  const _Float16* vbb = pv + (size_t)b * 32 * 16 * 64 * 8;

  // prologue: stage K0, V0, K1 (12 loads; aq's 8 loads precede them)
#pragma unroll
  for (int i = 0; i < 4; ++i) g2lds16(kbb + (size_t)(i * 256 + t) * 8, &Ks[0][(i * 256 + t) * 8]);
#pragma unroll
  for (int i = 0; i < 4; ++i) g2lds16(vbb + (size_t)(i * 256 + t) * 8, &Vs[0][(i * 256 + t) * 8]);
#pragma unroll
  for (int i = 0; i < 4; ++i) g2lds16(kbb + 8192 + (size_t)(i * 256 + t) * 8, &Ks[1][(i * 256 + t) * 8]);

  // K0 landed (retires aq + K0; V0,K1 = 8 stay in flight)
  asm volatile("s_waitcnt vmcnt(8)" ::: "memory");
  __builtin_amdgcn_s_barrier();
  asm volatile("" ::: "memory");

  // QK(0) -> Sp
  f32x4 Sp[2]; Sp[0] = zero; Sp[1] = zero;
  {
    const _Float16* ks = Ks[0];
    __builtin_amdgcn_s_setprio(1);
#pragma unroll
    for (int kk = 0; kk < 8; ++kk)
#pragma unroll
      for (int nt = 0; nt < 2; ++nt) {
        f16x8 bk_ = *(const f16x8*)&ks[((nt * 8 + kk) * 64 + lane) * 8];
        Sp[nt] = __builtin_amdgcn_mfma_f32_16x16x32_f16(bk_, aq[kk], Sp[nt], 0, 0, 0);
      }
    __builtin_amdgcn_s_setprio(0);
  }

  asm volatile("" ::: "memory");
  __builtin_amdgcn_s_barrier();        // all waves done reading Ks[0]
  // issue K2 -> Ks[0], V1 -> Vs[1]
#pragma unroll
  for (int i = 0; i < 4; ++i) g2lds16(kbb + 2 * 8192 + (size_t)(i * 256 + t) * 8, &Ks[0][(i * 256 + t) * 8]);
#pragma unroll
  for (int i = 0; i < 4; ++i) g2lds16(vbb + 1 * 8192 + (size_t)(i * 256 + t) * 8, &Vs[1][(i * 256 + t) * 8]);

  for (int kt = 1; kt < 32; ++kt) {
    // retire K[kt], V[kt-1]; keep K[kt+1], V[kt] in flight
    if (kt < 31) asm volatile("s_waitcnt vmcnt(8)" ::: "memory");
    else         asm volatile("s_waitcnt vmcnt(4)" ::: "memory");
    __builtin_amdgcn_s_barrier();
    asm volatile("" ::: "memory");

    // QK(kt) -> Sc (independent of SM/PV below)
    const _Float16* ks = Ks[kt & 1];
    f32x4 Sc[2]; Sc[0] = zero; Sc[1] = zero;
    __builtin_amdgcn_s_setprio(1);
#pragma unroll
    for (int kk = 0; kk < 8; ++kk)
#pragma unroll
      for (int nt = 0; nt < 2; ++nt) {
        f16x8 bk_ = *(const f16x8*)&ks[((nt * 8 + kk) * 64 + lane) * 8];
        Sc[nt] = __builtin_amdgcn_mfma_f32_16x16x32_f16(bk_, aq[kk], Sc[nt], 0, 0, 0);
      }
    __builtin_amdgcn_s_setprio(0);

    // SM(kt-1): operands ready since last iteration -> no MFMA-result stall
    float sv[8];
#pragma unroll
    for (int nt = 0; nt < 2; ++nt)
#pragma unroll
      for (int r = 0; r < 4; ++r) sv[nt * 4 + r] = Sp[nt][r];
    float vmax = sv[0];
#pragma unroll
    for (int j = 1; j < 8; ++j) vmax = fmaxf(vmax, sv[j]);
    vmax = fmaxf(vmax, __shfl_xor(vmax, 16));
    vmax = fmaxf(vmax, __shfl_xor(vmax, 32));
    if (__ballot(vmax > m_i + 8.0f)) {   // T13 defer-max
      float nm = fmaxf(m_i, vmax);
      float alpha = __expf(m_i - nm);
      float a4[4];
#pragma unroll
      for (int r = 0; r < 4; ++r) a4[r] = __shfl(alpha, quad * 4 + r);
#pragma unroll
      for (int dt = 0; dt < 16; ++dt)
#pragma unroll
        for (int r = 0; r < 4; ++r) O[dt][r] *= a4[r];
      l_i *= alpha;
      m_i = nm;
    }
    float rs = 0.f;
    H8 px;
#pragma unroll
    for (int j = 0; j < 8; ++j) {
      float pj = __expf(sv[j] - m_i);  // bounded by e^8 < fp16 max
      rs += pj;
      px.s[j] = (_Float16)pj;
    }
    rs += __shfl_xor(rs, 16);
    rs += __shfl_xor(rs, 32);
    l_i += rs;
    f16x8 ap = px.v;

    // PV(kt-1)
    const _Float16* vs = Vs[(kt - 1) & 1];
    __builtin_amdgcn_s_setprio(1);
#pragma unroll
    for (int dt = 0; dt < 16; ++dt) {
      f16x8 bv_ = *(const f16x8*)&vs[(dt * 64 + lane) * 8];
      O[dt] = __builtin_amdgcn_mfma_f32_16x16x32_f16(ap, bv_, O[dt], 0, 0, 0);
    }
    __builtin_amdgcn_s_setprio(0);

    asm volatile("" ::: "memory");
    __builtin_amdgcn_s_barrier();      // done reading Ks[kt&1], Vs[(kt-1)&1]
    if (kt <= 29) {                    // K[kt+2] -> retired K buffer
      const _Float16* kg = kbb + (size_t)(kt + 2) * 8192;
      _Float16* kd = Ks[kt & 1];
#pragma unroll
      for (int i = 0; i < 4; ++i) g2lds16(kg + (size_t)(i * 256 + t) * 8, kd + (i * 256 + t) * 8);
    }
    if (kt <= 30) {                    // V[kt+1] -> buffer PV(kt-1) just vacated
      const _Float16* vg = vbb + (size_t)(kt + 1) * 8192;
      _Float16* vd = Vs[(kt + 1) & 1];
#pragma unroll
      for (int i = 0; i < 4; ++i) g2lds16(vg + (size_t)(i * 256 + t) * 8, vd + (i * 256 + t) * 8);
    }
    Sp[0] = Sc[0]; Sp[1] = Sc[1];
  }

  // tail: SM(31) + PV(31) (V31 in Vs[1])
  asm volatile("s_waitcnt vmcnt(0)" ::: "memory");
  __builtin_amdgcn_s_barrier();
  asm volatile("" ::: "memory");
  {
    float sv[8];
#pragma unroll
    for (int nt = 0; nt < 2; ++nt)
#pragma unroll
      for (int r = 0; r < 4; ++r) sv[nt * 4 + r] = Sp[nt][r];
    float vmax = sv[0];
#pragma unroll
    for (int j = 1; j < 8; ++j) vmax = fmaxf(vmax, sv[j]);
    vmax = fmaxf(vmax, __shfl_xor(vmax, 16));
    vmax = fmaxf(vmax, __shfl_xor(vmax, 32));
    if (__ballot(vmax > m_i + 8.0f)) {
      float nm = fmaxf(m_i, vmax);
      float alpha = __expf(m_i - nm);
      float a4[4];
#pragma unroll
      for (int r = 0; r < 4; ++r) a4[r] = __shfl(alpha, quad * 4 + r);
#pragma unroll
      for (int dt = 0; dt < 16; ++dt)
#pragma unroll
        for (int r = 0; r < 4; ++r) O[dt][r] *= a4[r];
      l_i *= alpha;
      m_i = nm;
    }
    float rs = 0.f;
    H8 px;
#pragma unroll
    for (int j = 0; j < 8; ++j) {
      float pj = __expf(sv[j] - m_i);
      rs += pj;
      px.s[j] = (_Float16)pj;
    }
    rs += __shfl_xor(rs, 16);
    rs += __shfl_xor(rs, 32);
    l_i += rs;
    f16x8 ap = px.v;
    const _Float16* vs = Vs[1];
    __builtin_amdgcn_s_setprio(1);
#pragma unroll
    for (int dt = 0; dt < 16; ++dt) {
      f16x8 bv_ = *(const f16x8*)&vs[(dt * 64 + lane) * 8];
      O[dt] = __builtin_amdgcn_mfma_f32_16x16x32_f16(ap, bv_, O[dt], 0, 0, 0);
    }
    __builtin_amdgcn_s_setprio(0);
  }

  // epilogue: O /= l (broadcast l to C-layout), fp32 store
  float linv[4];
#pragma unroll
  for (int r = 0; r < 4; ++r) linv[r] = 1.0f / __shfl(l_i, quad * 4 + r);
#pragma unroll
  for (int r = 0; r < 4; ++r) {
    float* orow = out + (size_t)(qrow0 + wave * 16 + quad * 4 + r) * DD;
#pragma unroll
    for (int dt = 0; dt < 16; ++dt)
      orow[dt * 16 + col16] = O[dt][r] * linv[r];
  }
}

// ---------------- launch -------------------------------------------------------------
extern "C" void kernel_launch(void* const* d_in, const int* in_sizes, int n_in,
                              void* d_out, int out_size, void* d_ws, size_t ws_size,
                              hipStream_t stream) {
  const float* traj = (const float*)d_in[0];
  const float* Wq   = (const float*)d_in[1];
  const float* bq   = (const float*)d_in[2];
  const float* Wk   = (const float*)d_in[3];
  const float* bk   = (const float*)d_in[4];
  const float* Wv   = (const float*)d_in[5];
  const float* bv   = (const float*)d_in[6];

  // workspace (fp16): pq 16MB | pk 16MB | pv 16MB | pw 0.4MB  (all packed fragment-major)
  _Float16* pq = (_Float16*)d_ws;
  _Float16* pk = pq + (size_t)32768 * 256;
  _Float16* pv = pk + (size_t)32768 * 256;
  _Float16* pw = pv + (size_t)32768 * 256;   // ~48.4 MB total

  wconv_kernel<<<96, 256, 0, stream>>>(Wq, Wk, Wv, pw);
  proj_kernel<<<512, 256, 0, stream>>>(traj, bq, bk, bv, pw, pq, pk, pv);
  attn_kernel<<<dim3(32, 16), 256, 0, stream>>>(pq, pk, pv, (float*)d_out);
}